// Round 1
// baseline (1311.963 us; speedup 1.0000x reference)
//
#include <hip/hip_runtime.h>

#define TILE   16
#define HALO   22      // TILE + 6
#define KK     7
#define NCLASS 49
#define IMW    256
#define IMH    256
#define HW     65536   // 256*256

__global__ __launch_bounds__(256, 2)
void gtnet_kernel(const float* __restrict__ im_input,
                  const float* __restrict__ gt_motion,
                  const float* __restrict__ m_kernel,
                  float* __restrict__ out_pred,
                  float* __restrict__ out_mask)
{
    // om: per-thread 49-class out_mask accumulator, class-major -> bank = tid%32 (conflict-free).
    // Reused later as the im halo staging buffer (needs 3*484 = 1452 floats, fits easily).
    __shared__ float  om[NCLASS * 256];          // 50176 B
    __shared__ float  Klds[NCLASS * NCLASS];     // 9604 B
    __shared__ float2 halo[HALO * HALO];         // 3872 B  -> total 63652 B (< 64 KB)

    const int tid = threadIdx.x;
    const int tx = tid & 15, ty = tid >> 4;
    const int x0 = blockIdx.x * TILE, y0 = blockIdx.y * TILE;
    const int b  = blockIdx.z;
    const int x = x0 + tx, y = y0 + ty;

    // ---- stage kernel table (vector-indexed reads happen in om-build) ----
    for (int i = tid; i < NCLASS * NCLASS; i += 256) Klds[i] = m_kernel[i];

    // ---- stage motion halo: store (ay = my+3, ax = mx+3), sentinel -8 when out of image ----
    const float* mot_x = gt_motion + (size_t)b * 2 * HW;  // channel 0 -> ax
    const float* mot_y = mot_x + HW;                      // channel 1 -> ay
    for (int i = tid; i < HALO * HALO; i += 256) {
        int hy = i / HALO, hx = i - hy * HALO;
        int gy = y0 - 3 + hy, gx = x0 - 3 + hx;
        float2 v;
        if (gy >= 0 && gy < IMH && gx >= 0 && gx < IMW) {
            int off = gy * IMW + gx;
            v.x = mot_y[off] + 3.0f;
            v.y = mot_x[off] + 3.0f;
        } else {
            v.x = -8.0f; v.y = -8.0f;
        }
        halo[i] = v;
    }

    // ---- zero own om slice (private: only this tid touches om[*,tid]) ----
    #pragma unroll
    for (int n = 0; n < NCLASS; n++) om[n * 256 + tid] = 0.0f;

    __syncthreads();

    // ---- m_mask: dense 49-channel write for own pixel (4 nonzeros) ----
    {
        float2 h = halo[(ty + 3) * HALO + (tx + 3)];
        float iyf = floorf(h.x), ixf = floorf(h.y);
        float fy = h.x - iyf,    fx = h.y - ixf;
        int   iy = (int)iyf,     ix = (int)ixf;
        float wyA[KK], wxB[KK];
        #pragma unroll
        for (int a = 0; a < KK; a++) {
            wyA[a] = (a == iy) ? (1.0f - fy) : ((a == iy + 1) ? fy : 0.0f);
            wxB[a] = (a == ix) ? (1.0f - fx) : ((a == ix + 1) ? fx : 0.0f);
        }
        float* mm = out_mask + (size_t)b * NCLASS * HW + y * IMW + x;
        #pragma unroll
        for (int a = 0; a < KK; a++)
            #pragma unroll
            for (int bb = 0; bb < KK; bb++)
                mm[(size_t)(a * KK + bb) * HW] = wyA[a] * wxB[bb];
    }

    // ---- out_mask build: 49 neighbors x 4 sparse classes, ds_add_f32 scatter ----
    #pragma unroll
    for (int u = 0; u < KK; u++) {
        #pragma unroll
        for (int v = 0; v < KK; v++) {
            const int s = u * KK + v;                  // kernel tap index (compile-time)
            float2 h = halo[(ty + u) * HALO + (tx + v)];
            float ayc = h.x, axc = h.y;
            float iyf = floorf(ayc), ixf = floorf(axc);
            float fy = ayc - iyf,    fx = axc - ixf;
            bool  valid = (ayc >= 0.0f);
            float wy0 = valid ? (1.0f - fy) : 0.0f;
            float wy1 = valid ? fy : 0.0f;
            int   n00 = valid ? ((int)iyf * KK + (int)ixf) : 0;
            const float* kb = &Klds[n00 * NCLASS + s];
            float k00 = kb[0];
            float k01 = kb[NCLASS];
            float k10 = kb[KK * NCLASS];
            float k11 = kb[(KK + 1) * NCLASS];
            float wx0 = 1.0f - fx;
            float* ob = &om[n00 * 256 + tid];
            atomicAdd(ob,           wy0 * wx0 * k00);
            atomicAdd(ob + 256,     wy0 * fx  * k01);
            atomicAdd(ob + 7 * 256, wy1 * wx0 * k10);
            atomicAdd(ob + 8 * 256, wy1 * fx  * k11);
        }
    }

    // ---- prefetch im halo into registers (latency hidden under W_eff) ----
    const float* imP = im_input + ((size_t)b * 6 + 3) * HW;  // last 3 channels
    float imreg[6];
    #pragma unroll
    for (int kk2 = 0; kk2 < 6; kk2++) {
        int i = tid + kk2 * 256;
        float val = 0.0f;
        if (i < 3 * HALO * HALO) {
            int c  = i / (HALO * HALO);
            int r  = i - c * (HALO * HALO);
            int hy = r / HALO, hx = r - hy * HALO;
            int gy = y0 - 3 + hy, gx = x0 - 3 + hx;
            if (gy >= 0 && gy < IMH && gx >= 0 && gx < IMW)
                val = imP[c * HW + gy * IMW + gx];
        }
        imreg[kk2] = val;
    }

    __syncthreads();   // om complete (also drains ds_add via barrier waitcnt)

    // ---- W_eff[t] = sum_n om[n] * K[n][t]  (K via wave-uniform s_load from global) ----
    float w[NCLASS];
    #pragma unroll
    for (int t = 0; t < NCLASS; t++) w[t] = 0.0f;
    for (int n = 0; n < NCLASS; n++) {
        float omn = om[n * 256 + tid];
        #pragma unroll
        for (int t = 0; t < NCLASS; t++)
            w[t] = fmaf(omn, m_kernel[n * NCLASS + t], w[t]);
    }

    __syncthreads();   // everyone done reading om

    // ---- restage im halo into om's LDS space ----
    float* iml = om;   // 3 planes of 484 floats
    #pragma unroll
    for (int kk2 = 0; kk2 < 6; kk2++) {
        int i = tid + kk2 * 256;
        if (i < 3 * HALO * HALO) iml[i] = imreg[kk2];
    }
    __syncthreads();

    // ---- apply effective per-pixel 7x7 kernel to the 3 channels ----
    float a0 = 0.0f, a1 = 0.0f, a2 = 0.0f;
    #pragma unroll
    for (int p = 0; p < KK; p++) {
        #pragma unroll
        for (int q = 0; q < KK; q++) {
            float wv = w[p * KK + q];
            int   hi = (ty + p) * HALO + (tx + q);
            a0 = fmaf(wv, iml[hi],                 a0);
            a1 = fmaf(wv, iml[hi + HALO * HALO],   a1);
            a2 = fmaf(wv, iml[hi + 2 * HALO * HALO], a2);
        }
    }
    float* pr = out_pred + (size_t)b * 3 * HW + y * IMW + x;
    pr[0]      = a0;
    pr[HW]     = a1;
    pr[2 * HW] = a2;
}

extern "C" void kernel_launch(void* const* d_in, const int* in_sizes, int n_in,
                              void* d_out, int out_size, void* d_ws, size_t ws_size,
                              hipStream_t stream) {
    const float* im_input  = (const float*)d_in[0];
    // d_in[1] = im_output: unused by the reference computation
    const float* gt_motion = (const float*)d_in[2];
    const float* m_kernel  = (const float*)d_in[3];

    float* pred = (float*)d_out;                        // (16,3,256,256)
    float* mask = pred + (size_t)16 * 3 * HW;           // (16,49,256,256)

    dim3 grid(IMW / TILE, IMH / TILE, 16);
    dim3 block(256);
    hipLaunchKernelGGL(gtnet_kernel, grid, block, 0, stream,
                       im_input, gt_motion, m_kernel, pred, mask);
}

// Round 2
// 1289.827 us; speedup vs baseline: 1.0172x; 1.0172x over previous
//
#include <hip/hip_runtime.h>

typedef __bf16 bf16x8 __attribute__((ext_vector_type(8)));
typedef float  f32x4  __attribute__((ext_vector_type(4)));

#define TILE   16
#define HALO   22      // TILE + 6
#define KK     7
#define NCLASS 49
#define IMW    256
#define IMH    256
#define HW     65536   // 256*256
#define HH     484     // HALO*HALO

__global__ __launch_bounds__(256, 2)
void gtnet_kernel(const float* __restrict__ im_input,
                  const float* __restrict__ gt_motion,
                  const float* __restrict__ m_kernel,
                  float* __restrict__ out_pred,
                  float* __restrict__ out_mask)
{
    // omW: first used as om accumulator (class-major om[n*256+px], conflict-free for
    // scatter + private zeroing), then reused as W (pixel-major W[px*49+t], odd stride
    // -> conflict-free readback). 49*256*4 = 50176 B.
    __shared__ float  omW[NCLASS * 256];
    __shared__ float2 halo[HH];                       // 3872 B (motion ay,ax; sentinel -8)
    __shared__ float  Klds[NCLASS * NCLASS];          // 9604 B (f32, for the sparse scatter)
    __shared__ __align__(16) __bf16 KT[64 * 72];      // 9216 B (B-operand K^T, zero-padded)
    __shared__ float  iml[3 * HH];                    // 5808 B (im halo)
    // total 78676 B -> 2 blocks/CU

    const int tid  = threadIdx.x;
    const int lane = tid & 63, wv_id = tid >> 6;
    const int tx = tid & 15, ty = tid >> 4;
    const int x0 = blockIdx.x * TILE, y0 = blockIdx.y * TILE;
    const int b  = blockIdx.z;
    const int x = x0 + tx, y = y0 + ty;

    // ---------------- phase 1: staging ----------------
    for (int i = tid; i < NCLASS * NCLASS; i += 256) Klds[i] = m_kernel[i];

    for (int i = tid; i < 64 * 72; i += 256) {
        int t = i / 72, n = i - t * 72;
        float v = (t < NCLASS && n < NCLASS) ? m_kernel[n * NCLASS + t] : 0.0f;
        KT[i] = (__bf16)v;
    }

    const float* mot_x = gt_motion + (size_t)b * 2 * HW;  // channel 0 -> ax
    const float* mot_y = mot_x + HW;                      // channel 1 -> ay
    for (int i = tid; i < HH; i += 256) {
        int hy = i / HALO, hx = i - hy * HALO;
        int gy = y0 - 3 + hy, gx = x0 - 3 + hx;
        float2 v;
        if (gy >= 0 && gy < IMH && gx >= 0 && gx < IMW) {
            int off = gy * IMW + gx;
            v.x = mot_y[off] + 3.0f;
            v.y = mot_x[off] + 3.0f;
        } else {
            v.x = -8.0f; v.y = -8.0f;
        }
        halo[i] = v;
    }

    #pragma unroll
    for (int n = 0; n < NCLASS; n++) omW[n * 256 + tid] = 0.0f;

    // issue im halo global loads early (consumed before the om barrier)
    const float* imP = im_input + ((size_t)b * 6 + 3) * HW;  // last 3 channels
    float imreg[6];
    #pragma unroll
    for (int k2 = 0; k2 < 6; k2++) {
        int i = tid + k2 * 256;
        float val = 0.0f;
        if (i < 3 * HH) {
            int c  = i / HH;
            int r  = i - c * HH;
            int hy = r / HALO, hx = r - hy * HALO;
            int gy = y0 - 3 + hy, gx = x0 - 3 + hx;
            if (gy >= 0 && gy < IMH && gx >= 0 && gx < IMW)
                val = imP[c * HW + gy * IMW + gx];
        }
        imreg[k2] = val;
    }

    __syncthreads();

    // ---------------- phase 2: m_mask dense write ----------------
    {
        float2 h = halo[(ty + 3) * HALO + (tx + 3)];
        float iyf = floorf(h.x), ixf = floorf(h.y);
        float fy = h.x - iyf,    fx = h.y - ixf;
        int   iy = (int)iyf,     ix = (int)ixf;
        float wyA[KK], wxB[KK];
        #pragma unroll
        for (int a = 0; a < KK; a++) {
            wyA[a] = (a == iy) ? (1.0f - fy) : ((a == iy + 1) ? fy : 0.0f);
            wxB[a] = (a == ix) ? (1.0f - fx) : ((a == ix + 1) ? fx : 0.0f);
        }
        float* mm = out_mask + (size_t)b * NCLASS * HW + y * IMW + x;
        #pragma unroll
        for (int a = 0; a < KK; a++)
            #pragma unroll
            for (int bb = 0; bb < KK; bb++)
                mm[(size_t)(a * KK + bb) * HW] = wyA[a] * wxB[bb];
    }

    // ---------------- phase 3: om scatter (4-sparse per neighbor) ----------------
    #pragma unroll
    for (int u = 0; u < KK; u++) {
        #pragma unroll
        for (int v = 0; v < KK; v++) {
            const int s = u * KK + v;
            float2 h = halo[(ty + u) * HALO + (tx + v)];
            float ayc = h.x, axc = h.y;
            float iyf = floorf(ayc), ixf = floorf(axc);
            float fy = ayc - iyf,    fx = axc - ixf;
            bool  valid = (ayc >= 0.0f);
            float wy0 = valid ? (1.0f - fy) : 0.0f;
            float wy1 = valid ? fy : 0.0f;
            int   n00 = valid ? ((int)iyf * KK + (int)ixf) : 0;
            const float* kb = &Klds[n00 * NCLASS + s];
            float k00 = kb[0];
            float k01 = kb[NCLASS];
            float k10 = kb[KK * NCLASS];
            float k11 = kb[(KK + 1) * NCLASS];
            float wx0 = 1.0f - fx;
            float* ob = &omW[n00 * 256 + tid];
            atomicAdd(ob,           wy0 * wx0 * k00);
            atomicAdd(ob + 256,     wy0 * fx  * k01);
            atomicAdd(ob + 7 * 256, wy1 * wx0 * k10);
            atomicAdd(ob + 8 * 256, wy1 * fx  * k11);
        }
    }

    // stage im halo into its LDS region (read much later, after barrier)
    #pragma unroll
    for (int k2 = 0; k2 < 6; k2++) {
        int i = tid + k2 * 256;
        if (i < 3 * HH) iml[i] = imreg[k2];
    }

    __syncthreads();   // om complete

    // ---------------- phase 4: load MFMA fragments ----------------
    // A[m][k]: m = lane&15 (pixel), k = (lane>>4)*8 + j (class n), per 16x16x32 bf16 layout
    bf16x8 af[2][4];   // [kiter][mtile]
    #pragma unroll
    for (int kit = 0; kit < 2; kit++) {
        #pragma unroll
        for (int mt = 0; mt < 4; mt++) {
            int px = wv_id * 64 + mt * 16 + (lane & 15);
            int k0 = kit * 32 + (lane >> 4) * 8;
            bf16x8 a;
            #pragma unroll
            for (int j = 0; j < 8; j++) {
                int n  = k0 + j;
                int nn = (n < NCLASS) ? n : (NCLASS - 1);   // clamp keeps LDS access in-bounds
                float v = omW[nn * 256 + px];
                a[j] = (__bf16)((n < NCLASS) ? v : 0.0f);
            }
            af[kit][mt] = a;
        }
    }
    // B[k][n-col]: col = lane&15 (t), k = (lane>>4)*8 + j (class n); element = K[n][t] = KT[t][n]
    bf16x8 bfr[2][4];  // [kiter][ntile]
    #pragma unroll
    for (int kit = 0; kit < 2; kit++) {
        #pragma unroll
        for (int nt = 0; nt < 4; nt++) {
            int t  = nt * 16 + (lane & 15);
            int k0 = kit * 32 + (lane >> 4) * 8;
            bfr[kit][nt] = *reinterpret_cast<const bf16x8*>(&KT[t * 72 + k0]);
        }
    }

    __syncthreads();   // all om reads done before W overwrites the region

    // ---------------- phase 5: MFMA GEMM  W[256x49] = om[256x49(pad64)] x K[49x49(pad)] ----
    f32x4 acc[4][4];
    #pragma unroll
    for (int mt = 0; mt < 4; mt++) {
        #pragma unroll
        for (int nt = 0; nt < 4; nt++) {
            f32x4 c = {0.0f, 0.0f, 0.0f, 0.0f};
            c = __builtin_amdgcn_mfma_f32_16x16x32_bf16(af[0][mt], bfr[0][nt], c, 0, 0, 0);
            c = __builtin_amdgcn_mfma_f32_16x16x32_bf16(af[1][mt], bfr[1][nt], c, 0, 0, 0);
            acc[mt][nt] = c;
        }
    }

    // writeback: C/D layout col=lane&15 (t), row=(lane>>4)*4+reg (px) -> W[px*49+t]
    #pragma unroll
    for (int mt = 0; mt < 4; mt++) {
        #pragma unroll
        for (int nt = 0; nt < 4; nt++) {
            int t = nt * 16 + (lane & 15);
            if (t < NCLASS) {
                #pragma unroll
                for (int r = 0; r < 4; r++) {
                    int px = wv_id * 64 + mt * 16 + (lane >> 4) * 4 + r;
                    omW[px * NCLASS + t] = acc[mt][nt][r];
                }
            }
        }
    }

    __syncthreads();   // W complete

    // ---------------- phase 6: apply effective 7x7 kernel ----------------
    float wv[NCLASS];
    #pragma unroll
    for (int t = 0; t < NCLASS; t++) wv[t] = omW[tid * NCLASS + t];

    float a0 = 0.0f, a1 = 0.0f, a2 = 0.0f;
    #pragma unroll
    for (int p = 0; p < KK; p++) {
        #pragma unroll
        for (int q = 0; q < KK; q++) {
            float wvv = wv[p * KK + q];
            int   hi = (ty + p) * HALO + (tx + q);
            a0 = fmaf(wvv, iml[hi],          a0);
            a1 = fmaf(wvv, iml[hi + HH],     a1);
            a2 = fmaf(wvv, iml[hi + 2 * HH], a2);
        }
    }
    float* pr = out_pred + (size_t)b * 3 * HW + y * IMW + x;
    pr[0]      = a0;
    pr[HW]     = a1;
    pr[2 * HW] = a2;
}

extern "C" void kernel_launch(void* const* d_in, const int* in_sizes, int n_in,
                              void* d_out, int out_size, void* d_ws, size_t ws_size,
                              hipStream_t stream) {
    const float* im_input  = (const float*)d_in[0];
    // d_in[1] = im_output: unused by the reference computation
    const float* gt_motion = (const float*)d_in[2];
    const float* m_kernel  = (const float*)d_in[3];

    float* pred = (float*)d_out;                        // (16,3,256,256)
    float* mask = pred + (size_t)16 * 3 * HW;           // (16,49,256,256)

    dim3 grid(IMW / TILE, IMH / TILE, 16);
    dim3 block(256);
    hipLaunchKernelGGL(gtnet_kernel, grid, block, 0, stream,
                       im_input, gt_motion, m_kernel, pred, mask);
}